// Round 14
// baseline (299.272 us; speedup 1.0000x reference)
//
#include <hip/hip_runtime.h>
#include <hip/hip_bf16.h>
#include <cstdint>

typedef __attribute__((ext_vector_type(8))) _Float16 f16x8;
typedef __attribute__((ext_vector_type(4))) float    f32x4;
typedef __attribute__((ext_vector_type(4))) int      int4v;

#define S_LEN   2048
#define HDIM    3584
#define NHEADS  28
#define KVHEADS 4
#define KVDIM   512
#define QKVDIM  4608

__device__ __forceinline__ void glds16(const void* g, void* l) {
    __builtin_amdgcn_global_load_lds((const __attribute__((address_space(1))) void*)g,
                                     (__attribute__((address_space(3))) void*)l, 16, 0, 0);
}

// ---------------- numerics (mirror reference op-for-op in f32) ----------------
__device__ __forceinline__ float fs_relu_fast_f(float x, float vmax) {
    float q = floorf(fmaxf(x, 0.0f) / vmax * 65536.0f) / 65536.0f * vmax;
    return fminf(q, vmax * (65535.0f / 65536.0f));
}
__device__ __forceinline__ float to_spike_f(float x) {
    float xf = fminf(fmaxf(x, -500.0f), 500.0f);
    float a  = fabsf(xf);
    float sg = (xf > 0.0f) ? 1.0f : ((xf < 0.0f) ? -1.0f : 0.0f);
    float q  = (a < 10.0f) ? fs_relu_fast_f(a, 10.0f) : fs_relu_fast_f(a, 500.0f);
    return q * sg;
}

// ---------------- fused f32 -> f16 convert over 5 segments (HBM-BW-bound) ----------------
struct CvtArgs {
    const float* src[5];
    _Float16*    dst[5];
    int          cum8[6];
};
__global__ void f32_to_f16_multi(CvtArgs a, int total8) {
    int i = blockIdx.x * blockDim.x + threadIdx.x;
    if (i >= total8) return;
    int s = 0;
    while (i >= a.cum8[s + 1]) s++;
    int j = i - a.cum8[s];
    const float4* p = (const float4*)a.src[s] + (long)j * 2;
    float4 x = p[0], y = p[1];
    f16x8 v;
    v[0] = (_Float16)x.x; v[1] = (_Float16)x.y; v[2] = (_Float16)x.z; v[3] = (_Float16)x.w;
    v[4] = (_Float16)y.x; v[5] = (_Float16)y.y; v[6] = (_Float16)y.z; v[7] = (_Float16)y.w;
    *((f16x8*)a.dst[s] + j) = v;
}

__global__ void concat_bias(const float* __restrict__ bq, const float* __restrict__ bk,
                            const float* __restrict__ bv, float* __restrict__ b) {
    int i = blockIdx.x * blockDim.x + threadIdx.x;
    if (i >= QKVDIM) return;
    float v;
    if (i < HDIM) v = bq[i];
    else if (i < HDIM + KVDIM) v = bk[i - HDIM];
    else v = bv[i - HDIM - KVDIM];
    b[i] = v;
}

// ---------------- GEMM: C[M][N] = A[M][K] @ B[N][K]^T + bias ----------------
// R7 version (best measured: 88.5-89.6us): 128x128 tile, BK=64 single-buffered
// (32KB LDS), 8 waves (2Mx4N), 2 barriers per K-step, T1 XCD swizzle.
// This is the plateau config - R5/R8/R9/R13 structural variants all >= it.
template <bool HALF_OUT>
__global__ __launch_bounds__(512) void gemm_bt(
    const _Float16* __restrict__ A,
    const _Float16* __restrict__ B,
    const float* __restrict__ bias,
    void* __restrict__ Cout,
    int M, int N, int K)
{
    __shared__ _Float16 As[128 * 64];
    __shared__ _Float16 Bs[128 * 64];
    int tid  = threadIdx.x;
    int lane = tid & 63, wid = tid >> 6;      // wid 0..7
    int wr = wid >> 2, wc = wid & 3;          // 2 x 4 wave grid
    int gx = gridDim.x;
    int flat = blockIdx.y * gx + blockIdx.x;
    int cpx = (gx * gridDim.y) >> 3;
    int nf  = (flat & 7) * cpx + (flat >> 3);
    int bm = (nf % gx) * 128;
    int bn = (nf / gx) * 128;
    int r16 = lane & 15, kg = (lane >> 4) * 8;

    int srow = lane >> 3;                     // 0..7
    int scol = ((lane & 7) ^ srow) * 8;       // inverse-swizzled global col (rule 21)

    f32x4 acc[4][2] = {};
    const _Float16* Abase = A + (long)bm * K;
    const _Float16* Bbase = B + (long)bn * K;

    for (int kt = 0; kt < K; kt += 64) {
        __syncthreads();                      // previous tile's ds_reads complete
        #pragma unroll
        for (int i = 0; i < 2; i++) {
            int rbase = (wid * 2 + i) * 8;    // 16 issues cover 128 rows
            glds16(Abase + (long)(rbase + srow) * K + kt + scol, (void*)&As[rbase * 64]);
            glds16(Bbase + (long)(rbase + srow) * K + kt + scol, (void*)&Bs[rbase * 64]);
        }
        __syncthreads();                      // stage drained
        f16x8 af[2][4], bfr[2][2];
        #pragma unroll
        for (int i = 0; i < 4; i++) {
            int ra = wr * 64 + i * 16 + r16;
            #pragma unroll
            for (int kk = 0; kk < 2; kk++) {
                int cb = kk * 64 + kg * 2;
                af[kk][i] = *(const f16x8*)((const char*)As + ra * 128 + (cb ^ ((ra & 7) << 4)));
            }
        }
        #pragma unroll
        for (int j = 0; j < 2; j++) {
            int rb = wc * 32 + j * 16 + r16;
            #pragma unroll
            for (int kk = 0; kk < 2; kk++) {
                int cb = kk * 64 + kg * 2;
                bfr[kk][j] = *(const f16x8*)((const char*)Bs + rb * 128 + (cb ^ ((rb & 7) << 4)));
            }
        }
        #pragma unroll
        for (int kk = 0; kk < 2; kk++)
            #pragma unroll
            for (int i = 0; i < 4; i++)
                #pragma unroll
                for (int j = 0; j < 2; j++)
                    acc[i][j] = __builtin_amdgcn_mfma_f32_16x16x32_f16(af[kk][i], bfr[kk][j], acc[i][j], 0, 0, 0);
    }

    int rg = (lane >> 4) * 4;
    #pragma unroll
    for (int i = 0; i < 4; i++) {
        #pragma unroll
        for (int j = 0; j < 2; j++) {
            int col = bn + wc * 32 + j * 16 + r16;
            float bv = bias ? bias[col] : 0.0f;
            #pragma unroll
            for (int r = 0; r < 4; r++) {
                int row = bm + wr * 64 + i * 16 + rg + r;
                if (HALF_OUT)
                    ((_Float16*)Cout)[(long)row * N + col] = (_Float16)(acc[i][j][r] + bv);
                else
                    ((float*)Cout)[(long)row * N + col] = acc[i][j][r] + bv;
            }
        }
    }
}

// ---------------- RoPE + to_spike, paired (d, d+64) lanes ----------------
__global__ void rope_spike(const _Float16* __restrict__ QKVh,
                           const float* __restrict__ cosb, const float* __restrict__ sinb,
                           _Float16* __restrict__ Qa, _Float16* __restrict__ Ka)
{
    const float scale = 0.08838834764831845f;
    int s  = blockIdx.x;
    int h  = blockIdx.y * 2 + (threadIdx.x >> 6);
    int d0 = threadIdx.x & 63;
    float c0 = cosb[s * 128 + d0], c1 = cosb[s * 128 + d0 + 64];
    float s0 = sinb[s * 128 + d0], s1 = sinb[s * 128 + d0 + 64];
    const _Float16* row;
    _Float16* dst;
    float qs;
    if (h < NHEADS) {
        row = QKVh + (long)s * QKVDIM + h * 128;
        dst = Qa + ((long)h * S_LEN + s) * 128;
        qs = scale;
    } else {
        int hk = h - NHEADS;
        row = QKVh + (long)s * QKVDIM + HDIM + hk * 128;
        dst = Ka + ((long)hk * S_LEN + s) * 128;
        qs = 1.0f;
    }
    float x0 = (float)row[d0], x1 = (float)row[d0 + 64];
    dst[d0]      = (_Float16)(to_spike_f(x0 * c0 - x1 * s0) * qs);
    dst[d0 + 64] = (_Float16)(to_spike_f(x1 * c1 + x0 * s1) * qs);
}

// ---------------- V transpose: f16 [2048][ld] -> Vt[512][2048] f16 ----------------
__global__ __launch_bounds__(256) void vtrans(const _Float16* __restrict__ Vf, int ld,
                                              _Float16* __restrict__ Vt)
{
    __shared__ float t[64][65];
    int sb = blockIdx.x * 64;
    int cb = blockIdx.y * 64;
    int tid = threadIdx.x;
    #pragma unroll
    for (int p = 0; p < 16; p++) {
        int r = p * 4 + (tid >> 6);
        t[r][tid & 63] = (float)Vf[(long)(sb + r) * ld + cb + (tid & 63)];
    }
    __syncthreads();
    #pragma unroll
    for (int p = 0; p < 8; p++) {
        int c  = p * 8 + (tid >> 5);
        int sl = (tid & 31) * 2;
        union { _Float16 h[2]; int i; } u;
        u.h[0] = (_Float16)t[sl][c];
        u.h[1] = (_Float16)t[sl + 1][c];
        *(int*)(Vt + (long)(cb + c) * S_LEN + sb + sl) = u.i;
    }
}

// ---------------- single-pass causal attention, 32 q-rows PER WAVE ----------------
// 128-row q-tiles, 4 waves; wave w owns rows qt*128+w*32..+31 as TWO 16-row fragments.
// K/V fragment loads are shared across the two row-fragments -> QK/PV LDS reads per
// q-row HALVE vs the 16-row/wave version (the measured ~50us LDS wall).
// kbq = (qt*128+w*32)>>6; waves skip kb>kbq wave-uniformly (barriers outside).
__global__ __launch_bounds__(256) void attn_kernel(
    const _Float16* __restrict__ Qa,   // [28][2048][128], pre-scaled
    const _Float16* __restrict__ Ka,   // [4][2048][128]
    const _Float16* __restrict__ Vt,   // [4][128][2048]
    _Float16* __restrict__ Oa)         // [2048][3584]
{
    int head = blockIdx.x;
    int qt   = (int)gridDim.y - 1 - (int)blockIdx.y;  // heavy tiles dispatch first
    int kvh  = head / 7;
    int tid = threadIdx.x, lane = tid & 63, wid = tid >> 6;

    __shared__ _Float16 Ks[64 * 128];   // [key][d], slot ^= key&7
    __shared__ _Float16 Vs[128 * 64];   // [d][key], slot ^= d&7
    __shared__ _Float16 Ps[4][32][72];  // per-wave 32x64 P tile, +8 pad

    int r16 = lane & 15;
    int kg  = (lane >> 4) * 8;
    int rg4 = (lane >> 4) << 2;
    int qlo = qt * 128 + wid * 32;

    f16x8 qf[2][4];
    #pragma unroll
    for (int fr = 0; fr < 2; fr++) {
        const _Float16* qbase = Qa + ((long)head * S_LEN + qlo + fr * 16 + r16) * 128 + kg;
        #pragma unroll
        for (int kk = 0; kk < 4; kk++) qf[fr][kk] = *(const f16x8*)(qbase + kk * 32);
    }

    const _Float16* Kbase = Ka + (long)kvh * S_LEN * 128;
    const _Float16* Vbase = Vt + (long)kvh * 128 * S_LEN;

    int kbq = qlo >> 6;                  // wave's diagonal key-block
    int nkb = 2 * qt + 2;

    int krow4 = lane >> 4;
    int kcol  = lane & 15;
    int vrow8 = lane >> 3;
    int vcol  = lane & 7;

    float m[2][4], sume[2][4];
    #pragma unroll
    for (int fr = 0; fr < 2; fr++)
        #pragma unroll
        for (int r = 0; r < 4; r++) { m[fr][r] = -1e30f; sume[fr][r] = 0.f; }
    f32x4 o[2][8] = {};

    for (int kb = 0; kb < nkb; kb++) {
        __syncthreads();
        #pragma unroll
        for (int i = 0; i < 4; i++) {
            int base = (wid * 4 + i) * 4;
            int row  = base + krow4;
            glds16(Kbase + (long)(kb * 64 + row) * 128 + ((kcol ^ (row & 7)) * 8),
                   (void*)&Ks[base * 128]);
        }
        #pragma unroll
        for (int i = 0; i < 4; i++) {
            int base = (wid * 4 + i) * 8;
            int dd   = base + vrow8;
            glds16(Vbase + (long)dd * S_LEN + kb * 64 + ((vcol ^ (dd & 7)) * 8),
                   (void*)&Vs[base * 64]);
        }
        __syncthreads();
        if (kb > kbq) continue;           // wave-uniform; no barriers inside

        // ---- QK^T: K-fragments loaded once, used for both row-fragments ----
        f32x4 c[2][4];
        #pragma unroll
        for (int n = 0; n < 4; n++) {
            c[0][n] = f32x4{0.f, 0.f, 0.f, 0.f};
            c[1][n] = f32x4{0.f, 0.f, 0.f, 0.f};
            int krow = n * 16 + r16;
            #pragma unroll
            for (int kk = 0; kk < 4; kk++) {
                int off = krow * 256 + ((kk * 64 + kg * 2) ^ ((krow & 7) << 4));
                f16x8 kf = *(const f16x8*)((const char*)Ks + off);
                c[0][n] = __builtin_amdgcn_mfma_f32_16x16x32_f16(qf[0][kk], kf, c[0][n], 0, 0, 0);
                c[1][n] = __builtin_amdgcn_mfma_f32_16x16x32_f16(qf[1][kk], kf, c[1][n], 0, 0, 0);
            }
        }
        // ---- causal mask: only the wave's diagonal block ----
        if (kb == kbq) {
            #pragma unroll
            for (int n = 0; n < 4; n++) {
                int key = kb * 64 + n * 16 + r16;
                #pragma unroll
                for (int fr = 0; fr < 2; fr++) {
                    int row0 = qlo + fr * 16 + rg4;
                    #pragma unroll
                    for (int r = 0; r < 4; r++)
                        if (key > row0 + r) c[fr][n][r] = -1e30f;
                }
            }
        }
        // ---- block max + deferred rescale (T13) ----
        float bmax[2][4];
        bool need = false;
        #pragma unroll
        for (int fr = 0; fr < 2; fr++)
            #pragma unroll
            for (int r = 0; r < 4; r++) {
                float bmv = fmaxf(fmaxf(c[fr][0][r], c[fr][1][r]),
                                  fmaxf(c[fr][2][r], c[fr][3][r]));
                bmv = fmaxf(bmv, __shfl_xor(bmv, 1));
                bmv = fmaxf(bmv, __shfl_xor(bmv, 2));
                bmv = fmaxf(bmv, __shfl_xor(bmv, 4));
                bmv = fmaxf(bmv, __shfl_xor(bmv, 8));
                bmax[fr][r] = bmv;
                need = need || (bmv > m[fr][r] + 8.0f);
            }
        if (__any(need)) {
            #pragma unroll
            for (int fr = 0; fr < 2; fr++)
                #pragma unroll
                for (int r = 0; r < 4; r++) {
                    float mn = fmaxf(m[fr][r], bmax[fr][r]);
                    float f  = __expf(m[fr][r] - mn);
                    m[fr][r] = mn;
                    sume[fr][r] *= f;
                    #pragma unroll
                    for (int db = 0; db < 8; db++) o[fr][db][r] *= f;
                }
        }
        // ---- e = exp(s - m), store P, accumulate per-lane sum ----
        #pragma unroll
        for (int fr = 0; fr < 2; fr++)
            #pragma unroll
            for (int n = 0; n < 4; n++)
                #pragma unroll
                for (int r = 0; r < 4; r++) {
                    float e = __expf(c[fr][n][r] - m[fr][r]);
                    sume[fr][r] += e;
                    Ps[wid][fr * 16 + rg4 + r][n * 16 + r16] = (_Float16)e;
                }
        // ---- PV: V-fragments loaded once, used for both row-fragments ----
        f16x8 pa[2][2];
        #pragma unroll
        for (int fr = 0; fr < 2; fr++)
            #pragma unroll
            for (int kk = 0; kk < 2; kk++)
                pa[fr][kk] = *(const f16x8*)&Ps[wid][fr * 16 + r16][kk * 32 + kg];
        #pragma unroll
        for (int db = 0; db < 8; db++) {
            #pragma unroll
            for (int kk = 0; kk < 2; kk++) {
                int vrow = db * 16 + r16;
                int off = vrow * 128 + ((kk * 64 + kg * 2) ^ ((vrow & 7) << 4));
                f16x8 vfr = *(const f16x8*)((const char*)Vs + off);
                o[0][db] = __builtin_amdgcn_mfma_f32_16x16x32_f16(pa[0][kk], vfr, o[0][db], 0, 0, 0);
                o[1][db] = __builtin_amdgcn_mfma_f32_16x16x32_f16(pa[1][kk], vfr, o[1][db], 0, 0, 0);
            }
        }
    }
    #pragma unroll
    for (int fr = 0; fr < 2; fr++) {
        #pragma unroll
        for (int r = 0; r < 4; r++) {
            float s = sume[fr][r];
            s += __shfl_xor(s, 1);
            s += __shfl_xor(s, 2);
            s += __shfl_xor(s, 4);
            s += __shfl_xor(s, 8);
            sume[fr][r] = s;
        }
        #pragma unroll
        for (int db = 0; db < 8; db++) {
            #pragma unroll
            for (int r = 0; r < 4; r++) {
                int row = qlo + fr * 16 + rg4 + r;
                int col = head * 128 + db * 16 + r16;
                Oa[(long)row * HDIM + col] = (_Float16)(o[fr][db][r] / sume[fr][r]);
            }
        }
    }
}

// ---------------- launch ----------------
extern "C" void kernel_launch(void* const* d_in, const int* in_sizes, int n_in,
                              void* d_out, int out_size, void* d_ws, size_t ws_size,
                              hipStream_t stream) {
    const float* hs   = (const float*)d_in[0];
    const float* cosb = (const float*)d_in[2];
    const float* sinb = (const float*)d_in[3];
    const float* wq   = (const float*)d_in[4];
    const float* bq   = (const float*)d_in[5];
    const float* wk   = (const float*)d_in[6];
    const float* bk   = (const float*)d_in[7];
    const float* wv   = (const float*)d_in[8];
    const float* bv   = (const float*)d_in[9];
    const float* wo   = (const float*)d_in[10];
    float* out = (float*)d_out;

    char* ws = (char*)d_ws;
    size_t off = 0;
    auto alloc = [&](size_t bytes) {
        void* p = ws + off;
        off += (bytes + 255) & ~(size_t)255;
        return p;
    };
    const long HS_N = (long)S_LEN * HDIM;    // 7,340,032
    const long WQ_N = (long)HDIM * HDIM;     // 12,845,056
    const long WK_N = (long)KVDIM * HDIM;    // 1,835,008
    const long KV_N = (long)S_LEN * KVDIM;   // 1,048,576
    const long QKV_N = (long)S_LEN * QKVDIM; // 9,437,184

    _Float16* hs_h   = (_Float16*)alloc(HS_N * 2);
    _Float16* wqkv_h = (_Float16*)alloc((WQ_N + 2 * WK_N) * 2);
    _Float16* wo_h   = (_Float16*)alloc(WQ_N * 2);
    float*    bqkv   = (float*)alloc(QKVDIM * 4);
    _Float16* QKVh   = (_Float16*)alloc(QKV_N * 2);
    _Float16* Ka     = (_Float16*)alloc(KV_N * 2);
    _Float16* Vt     = (_Float16*)alloc(KV_N * 2);
    _Float16* Qa     = hs_h;             // hs_h dead after QKV GEMM
    _Float16* Oattn  = QKVh;             // QKVh dead after rope+vtrans

    CvtArgs ca;
    ca.src[0] = hs;  ca.dst[0] = hs_h;
    ca.src[1] = wq;  ca.dst[1] = wqkv_h;
    ca.src[2] = wk;  ca.dst[2] = wqkv_h + WQ_N;
    ca.src[3] = wv;  ca.dst[3] = wqkv_h + WQ_N + WK_N;
    ca.src[4] = wo;  ca.dst[4] = wo_h;
    int n8[5] = {(int)(HS_N / 8), (int)(WQ_N / 8), (int)(WK_N / 8), (int)(WK_N / 8), (int)(WQ_N / 8)};
    ca.cum8[0] = 0;
    for (int i = 0; i < 5; i++) ca.cum8[i + 1] = ca.cum8[i] + n8[i];
    int total8 = ca.cum8[5];
    f32_to_f16_multi<<<(total8 + 255) / 256, 256, 0, stream>>>(ca, total8);
    concat_bias<<<(QKVDIM + 255) / 256, 256, 0, stream>>>(bq, bk, bv, bqkv);

    gemm_bt<true><<<dim3(16, 36), 512, 0, stream>>>(hs_h, wqkv_h, bqkv, QKVh, S_LEN, QKVDIM, HDIM);

    rope_spike<<<dim3(S_LEN, 16), 128, 0, stream>>>(QKVh, cosb, sinb, Qa, Ka);
    vtrans<<<dim3(S_LEN / 64, KVDIM / 64), 256, 0, stream>>>(QKVh + HDIM + KVDIM, QKVDIM, Vt);

    attn_kernel<<<dim3(NHEADS, S_LEN / 128), 256, 0, stream>>>(Qa, Ka, Vt, Oattn);

    gemm_bt<false><<<dim3(16, 28), 512, 0, stream>>>(Oattn, wo_h, nullptr, out, S_LEN, HDIM, HDIM);
}

// Round 15
// 273.458 us; speedup vs baseline: 1.0944x; 1.0944x over previous
//
#include <hip/hip_runtime.h>
#include <hip/hip_bf16.h>
#include <cstdint>

typedef __attribute__((ext_vector_type(8))) _Float16 f16x8;
typedef __attribute__((ext_vector_type(4))) float    f32x4;
typedef __attribute__((ext_vector_type(4))) int      int4v;

#define S_LEN   2048
#define HDIM    3584
#define NHEADS  28
#define KVHEADS 4
#define KVDIM   512
#define QKVDIM  4608

__device__ __forceinline__ void glds16(const void* g, void* l) {
    __builtin_amdgcn_global_load_lds((const __attribute__((address_space(1))) void*)g,
                                     (__attribute__((address_space(3))) void*)l, 16, 0, 0);
}

// ---------------- numerics (mirror reference op-for-op in f32) ----------------
__device__ __forceinline__ float fs_relu_fast_f(float x, float vmax) {
    float q = floorf(fmaxf(x, 0.0f) / vmax * 65536.0f) / 65536.0f * vmax;
    return fminf(q, vmax * (65535.0f / 65536.0f));
}
__device__ __forceinline__ float to_spike_f(float x) {
    float xf = fminf(fmaxf(x, -500.0f), 500.0f);
    float a  = fabsf(xf);
    float sg = (xf > 0.0f) ? 1.0f : ((xf < 0.0f) ? -1.0f : 0.0f);
    float q  = (a < 10.0f) ? fs_relu_fast_f(a, 10.0f) : fs_relu_fast_f(a, 500.0f);
    return q * sg;
}

// ---------------- fused f32 -> f16 convert over 5 segments (~5.9 TB/s, BW roofline) ----------------
struct CvtArgs {
    const float* src[5];
    _Float16*    dst[5];
    int          cum8[6];
};
__global__ void f32_to_f16_multi(CvtArgs a, int total8) {
    int i = blockIdx.x * blockDim.x + threadIdx.x;
    if (i >= total8) return;
    int s = 0;
    while (i >= a.cum8[s + 1]) s++;
    int j = i - a.cum8[s];
    const float4* p = (const float4*)a.src[s] + (long)j * 2;
    float4 x = p[0], y = p[1];
    f16x8 v;
    v[0] = (_Float16)x.x; v[1] = (_Float16)x.y; v[2] = (_Float16)x.z; v[3] = (_Float16)x.w;
    v[4] = (_Float16)y.x; v[5] = (_Float16)y.y; v[6] = (_Float16)y.z; v[7] = (_Float16)y.w;
    *((f16x8*)a.dst[s] + j) = v;
}

__global__ void concat_bias(const float* __restrict__ bq, const float* __restrict__ bk,
                            const float* __restrict__ bv, float* __restrict__ b) {
    int i = blockIdx.x * blockDim.x + threadIdx.x;
    if (i >= QKVDIM) return;
    float v;
    if (i < HDIM) v = bq[i];
    else if (i < HDIM + KVDIM) v = bk[i - HDIM];
    else v = bv[i - HDIM - KVDIM];
    b[i] = v;
}

// ---------------- GEMM: C[M][N] = A[M][K] @ B[N][K]^T + bias ----------------
// R7 version (best measured: 88.5-89.6us): 128x128 tile, BK=64 single-buffered
// (32KB LDS), 8 waves (2Mx4N), 2 barriers per K-step, T1 XCD swizzle.
// Plateau config: R5/R8/R9/R11/R13 structural variants all measured >= this.
template <bool HALF_OUT>
__global__ __launch_bounds__(512) void gemm_bt(
    const _Float16* __restrict__ A,
    const _Float16* __restrict__ B,
    const float* __restrict__ bias,
    void* __restrict__ Cout,
    int M, int N, int K)
{
    __shared__ _Float16 As[128 * 64];
    __shared__ _Float16 Bs[128 * 64];
    int tid  = threadIdx.x;
    int lane = tid & 63, wid = tid >> 6;      // wid 0..7
    int wr = wid >> 2, wc = wid & 3;          // 2 x 4 wave grid
    int gx = gridDim.x;
    int flat = blockIdx.y * gx + blockIdx.x;
    int cpx = (gx * gridDim.y) >> 3;
    int nf  = (flat & 7) * cpx + (flat >> 3);
    int bm = (nf % gx) * 128;
    int bn = (nf / gx) * 128;
    int r16 = lane & 15, kg = (lane >> 4) * 8;

    int srow = lane >> 3;                     // 0..7
    int scol = ((lane & 7) ^ srow) * 8;       // inverse-swizzled global col (rule 21)

    f32x4 acc[4][2] = {};
    const _Float16* Abase = A + (long)bm * K;
    const _Float16* Bbase = B + (long)bn * K;

    for (int kt = 0; kt < K; kt += 64) {
        __syncthreads();                      // previous tile's ds_reads complete
        #pragma unroll
        for (int i = 0; i < 2; i++) {
            int rbase = (wid * 2 + i) * 8;    // 16 issues cover 128 rows
            glds16(Abase + (long)(rbase + srow) * K + kt + scol, (void*)&As[rbase * 64]);
            glds16(Bbase + (long)(rbase + srow) * K + kt + scol, (void*)&Bs[rbase * 64]);
        }
        __syncthreads();                      // stage drained
        f16x8 af[2][4], bfr[2][2];
        #pragma unroll
        for (int i = 0; i < 4; i++) {
            int ra = wr * 64 + i * 16 + r16;
            #pragma unroll
            for (int kk = 0; kk < 2; kk++) {
                int cb = kk * 64 + kg * 2;
                af[kk][i] = *(const f16x8*)((const char*)As + ra * 128 + (cb ^ ((ra & 7) << 4)));
            }
        }
        #pragma unroll
        for (int j = 0; j < 2; j++) {
            int rb = wc * 32 + j * 16 + r16;
            #pragma unroll
            for (int kk = 0; kk < 2; kk++) {
                int cb = kk * 64 + kg * 2;
                bfr[kk][j] = *(const f16x8*)((const char*)Bs + rb * 128 + (cb ^ ((rb & 7) << 4)));
            }
        }
        #pragma unroll
        for (int kk = 0; kk < 2; kk++)
            #pragma unroll
            for (int i = 0; i < 4; i++)
                #pragma unroll
                for (int j = 0; j < 2; j++)
                    acc[i][j] = __builtin_amdgcn_mfma_f32_16x16x32_f16(af[kk][i], bfr[kk][j], acc[i][j], 0, 0, 0);
    }

    int rg = (lane >> 4) * 4;
    #pragma unroll
    for (int i = 0; i < 4; i++) {
        #pragma unroll
        for (int j = 0; j < 2; j++) {
            int col = bn + wc * 32 + j * 16 + r16;
            float bv = bias ? bias[col] : 0.0f;
            #pragma unroll
            for (int r = 0; r < 4; r++) {
                int row = bm + wr * 64 + i * 16 + rg + r;
                if (HALF_OUT)
                    ((_Float16*)Cout)[(long)row * N + col] = (_Float16)(acc[i][j][r] + bv);
                else
                    ((float*)Cout)[(long)row * N + col] = acc[i][j][r] + bv;
            }
        }
    }
}

// ---------------- RoPE + to_spike, paired (d, d+64) lanes ----------------
// grid (S, 16), block 128: h = by*2 + (tid>>6); lane d0 handles d0 and d0+64.
// Q pre-scaled by 1/sqrt(128).
__global__ void rope_spike(const _Float16* __restrict__ QKVh,
                           const float* __restrict__ cosb, const float* __restrict__ sinb,
                           _Float16* __restrict__ Qa, _Float16* __restrict__ Ka)
{
    const float scale = 0.08838834764831845f;
    int s  = blockIdx.x;
    int h  = blockIdx.y * 2 + (threadIdx.x >> 6);
    int d0 = threadIdx.x & 63;
    float c0 = cosb[s * 128 + d0], c1 = cosb[s * 128 + d0 + 64];
    float s0 = sinb[s * 128 + d0], s1 = sinb[s * 128 + d0 + 64];
    const _Float16* row;
    _Float16* dst;
    float qs;
    if (h < NHEADS) {
        row = QKVh + (long)s * QKVDIM + h * 128;
        dst = Qa + ((long)h * S_LEN + s) * 128;
        qs = scale;
    } else {
        int hk = h - NHEADS;
        row = QKVh + (long)s * QKVDIM + HDIM + hk * 128;
        dst = Ka + ((long)hk * S_LEN + s) * 128;
        qs = 1.0f;
    }
    float x0 = (float)row[d0], x1 = (float)row[d0 + 64];
    dst[d0]      = (_Float16)(to_spike_f(x0 * c0 - x1 * s0) * qs);
    dst[d0 + 64] = (_Float16)(to_spike_f(x1 * c1 + x0 * s1) * qs);
}

// ---------------- V transpose: f16 [2048][ld] -> Vt[512][2048] f16 ----------------
__global__ __launch_bounds__(256) void vtrans(const _Float16* __restrict__ Vf, int ld,
                                              _Float16* __restrict__ Vt)
{
    __shared__ float t[64][65];
    int sb = blockIdx.x * 64;
    int cb = blockIdx.y * 64;
    int tid = threadIdx.x;
    #pragma unroll
    for (int p = 0; p < 16; p++) {
        int r = p * 4 + (tid >> 6);
        t[r][tid & 63] = (float)Vf[(long)(sb + r) * ld + cb + (tid & 63)];
    }
    __syncthreads();
    #pragma unroll
    for (int p = 0; p < 8; p++) {
        int c  = p * 8 + (tid >> 5);
        int sl = (tid & 31) * 2;
        union { _Float16 h[2]; int i; } u;
        u.h[0] = (_Float16)t[sl][c];
        u.h[1] = (_Float16)t[sl + 1][c];
        *(int*)(Vt + (long)(cb + c) * S_LEN + sb + sl) = u.i;
    }
}

// ---------------- single-pass causal attention, online softmax (best: 4-wave/64-row) ----------------
// 64-row q-tiles, 4 waves (wave w owns rows qt*64+w*16..+15), key blocks of 64.
// R14 showed 32-rows/wave (VGPR 152, occ 9.6%) and R12 showed 8-wave/128-row both lose
// to this: occupancy dominates LDS traffic at this geometry.
__global__ __launch_bounds__(256) void attn_kernel(
    const _Float16* __restrict__ Qa,   // [28][2048][128], pre-scaled
    const _Float16* __restrict__ Ka,   // [4][2048][128]
    const _Float16* __restrict__ Vt,   // [4][128][2048]
    _Float16* __restrict__ Oa)         // [2048][3584]
{
    int head = blockIdx.x;
    int qt   = (int)gridDim.y - 1 - (int)blockIdx.y;
    int kvh  = head / 7;
    int tid = threadIdx.x, lane = tid & 63, wid = tid >> 6;

    __shared__ _Float16 Ks[64 * 128];   // [key][d], byte ^= (key&7)<<4
    __shared__ _Float16 Vs[128 * 64];   // [d][key], byte ^= (d&7)<<4
    __shared__ _Float16 Ps[4][16][72];

    int r16 = lane & 15;
    int kg  = (lane >> 4) * 8;
    int qrow = qt * 64 + wid * 16 + r16;
    f16x8 qf[4];
    const _Float16* qbase = Qa + ((long)head * S_LEN + qrow) * 128 + kg;
    #pragma unroll
    for (int kk = 0; kk < 4; kk++) qf[kk] = *(const f16x8*)(qbase + kk * 32);

    const _Float16* Kbase = Ka + (long)kvh * S_LEN * 128;
    const _Float16* Vbase = Vt + (long)kvh * 128 * S_LEN;

    int nkb = qt + 1;
    int qr0 = qt * 64 + wid * 16 + ((lane >> 4) << 2);

    int krow4 = lane >> 4;
    int kcol  = lane & 15;
    int vrow8 = lane >> 3;
    int vcol  = lane & 7;

    float m[4]    = {-1e30f, -1e30f, -1e30f, -1e30f};
    float sume[4] = {0.f, 0.f, 0.f, 0.f};
    f32x4 o[8] = {};

    for (int kb = 0; kb < nkb; kb++) {
        __syncthreads();
        #pragma unroll
        for (int i = 0; i < 4; i++) {
            int base = (wid * 4 + i) * 4;
            int row  = base + krow4;
            glds16(Kbase + (long)(kb * 64 + row) * 128 + ((kcol ^ (row & 7)) * 8),
                   (void*)&Ks[base * 128]);
        }
        #pragma unroll
        for (int i = 0; i < 4; i++) {
            int base = (wid * 4 + i) * 8;
            int dd   = base + vrow8;
            glds16(Vbase + (long)dd * S_LEN + kb * 64 + ((vcol ^ (dd & 7)) * 8),
                   (void*)&Vs[base * 64]);
        }
        __syncthreads();

        // ---- QK^T (scores already scaled via Q) ----
        f32x4 c[4];
        #pragma unroll
        for (int n = 0; n < 4; n++) {
            c[n] = f32x4{0.f, 0.f, 0.f, 0.f};
            #pragma unroll
            for (int kk = 0; kk < 4; kk++) {
                int krow = n * 16 + r16;
                int off = krow * 256 + ((kk * 64 + kg * 2) ^ ((krow & 7) << 4));
                f16x8 kf = *(const f16x8*)((const char*)Ks + off);
                c[n] = __builtin_amdgcn_mfma_f32_16x16x32_f16(qf[kk], kf, c[n], 0, 0, 0);
            }
        }
        // ---- causal mask: wave-uniform branch, diagonal block only ----
        if (kb == qt) {
            #pragma unroll
            for (int n = 0; n < 4; n++) {
                int key = kb * 64 + n * 16 + r16;
                #pragma unroll
                for (int r = 0; r < 4; r++)
                    if (key > qr0 + r) c[n][r] = -1e30f;
            }
        }
        // ---- block max + deferred rescale (T13) ----
        float bmax[4];
        #pragma unroll
        for (int r = 0; r < 4; r++) {
            float bmv = fmaxf(fmaxf(c[0][r], c[1][r]), fmaxf(c[2][r], c[3][r]));
            bmv = fmaxf(bmv, __shfl_xor(bmv, 1));
            bmv = fmaxf(bmv, __shfl_xor(bmv, 2));
            bmv = fmaxf(bmv, __shfl_xor(bmv, 4));
            bmv = fmaxf(bmv, __shfl_xor(bmv, 8));
            bmax[r] = bmv;
        }
        bool need = (bmax[0] > m[0] + 8.0f) | (bmax[1] > m[1] + 8.0f) |
                    (bmax[2] > m[2] + 8.0f) | (bmax[3] > m[3] + 8.0f);
        if (__any(need)) {
            #pragma unroll
            for (int r = 0; r < 4; r++) {
                float mn = fmaxf(m[r], bmax[r]);
                float f  = __expf(m[r] - mn);
                m[r] = mn;
                sume[r] *= f;
                #pragma unroll
                for (int db = 0; db < 8; db++) o[db][r] *= f;
            }
        }
        // ---- e = exp(s - m), store P, accumulate per-lane sum ----
        #pragma unroll
        for (int n = 0; n < 4; n++) {
            #pragma unroll
            for (int r = 0; r < 4; r++) {
                float e = __expf(c[n][r] - m[r]);
                sume[r] += e;
                Ps[wid][(lane >> 4) * 4 + r][n * 16 + r16] = (_Float16)e;
            }
        }
        // ---- PV (same-wave LDS dependency) ----
        f16x8 pa[2];
        #pragma unroll
        for (int kk = 0; kk < 2; kk++)
            pa[kk] = *(const f16x8*)&Ps[wid][r16][kk * 32 + kg];
        #pragma unroll
        for (int db = 0; db < 8; db++) {
            #pragma unroll
            for (int kk = 0; kk < 2; kk++) {
                int vrow = db * 16 + r16;
                int off = vrow * 128 + ((kk * 64 + kg * 2) ^ ((vrow & 7) << 4));
                f16x8 vfr = *(const f16x8*)((const char*)Vs + off);
                o[db] = __builtin_amdgcn_mfma_f32_16x16x32_f16(pa[kk], vfr, o[db], 0, 0, 0);
            }
        }
    }
    #pragma unroll
    for (int r = 0; r < 4; r++) {
        float s = sume[r];
        s += __shfl_xor(s, 1);
        s += __shfl_xor(s, 2);
        s += __shfl_xor(s, 4);
        s += __shfl_xor(s, 8);
        sume[r] = s;
    }
    #pragma unroll
    for (int db = 0; db < 8; db++) {
        #pragma unroll
        for (int r = 0; r < 4; r++) {
            int row = qt * 64 + wid * 16 + (lane >> 4) * 4 + r;
            int col = head * 128 + db * 16 + r16;
            Oa[(long)row * HDIM + col] = (_Float16)(o[db][r] / sume[r]);
        }
    }
}

// ---------------- launch ----------------
extern "C" void kernel_launch(void* const* d_in, const int* in_sizes, int n_in,
                              void* d_out, int out_size, void* d_ws, size_t ws_size,
                              hipStream_t stream) {
    const float* hs   = (const float*)d_in[0];
    const float* cosb = (const float*)d_in[2];
    const float* sinb = (const float*)d_in[3];
    const float* wq   = (const float*)d_in[4];
    const float* bq   = (const float*)d_in[5];
    const float* wk   = (const float*)d_in[6];
    const float* bk   = (const float*)d_in[7];
    const float* wv   = (const float*)d_in[8];
    const float* bv   = (const float*)d_in[9];
    const float* wo   = (const float*)d_in[10];
    float* out = (float*)d_out;

    char* ws = (char*)d_ws;
    size_t off = 0;
    auto alloc = [&](size_t bytes) {
        void* p = ws + off;
        off += (bytes + 255) & ~(size_t)255;
        return p;
    };
    const long HS_N = (long)S_LEN * HDIM;    // 7,340,032
    const long WQ_N = (long)HDIM * HDIM;     // 12,845,056
    const long WK_N = (long)KVDIM * HDIM;    // 1,835,008
    const long KV_N = (long)S_LEN * KVDIM;   // 1,048,576
    const long QKV_N = (long)S_LEN * QKVDIM; // 9,437,184

    _Float16* hs_h   = (_Float16*)alloc(HS_N * 2);
    _Float16* wqkv_h = (_Float16*)alloc((WQ_N + 2 * WK_N) * 2);
    _Float16* wo_h   = (_Float16*)alloc(WQ_N * 2);
    float*    bqkv   = (float*)alloc(QKVDIM * 4);
    _Float16* QKVh   = (_Float16*)alloc(QKV_N * 2);
    _Float16* Ka     = (_Float16*)alloc(KV_N * 2);
    _Float16* Vt     = (_Float16*)alloc(KV_N * 2);
    _Float16* Qa     = hs_h;             // hs_h dead after QKV GEMM
    _Float16* Oattn  = QKVh;             // QKVh dead after rope+vtrans

    CvtArgs ca;
    ca.src[0] = hs;  ca.dst[0] = hs_h;
    ca.src[1] = wq;  ca.dst[1] = wqkv_h;
    ca.src[2] = wk;  ca.dst[2] = wqkv_h + WQ_N;
    ca.src[3] = wv;  ca.dst[3] = wqkv_h + WQ_N + WK_N;
    ca.src[4] = wo;  ca.dst[4] = wo_h;
    int n8[5] = {(int)(HS_N / 8), (int)(WQ_N / 8), (int)(WK_N / 8), (int)(WK_N / 8), (int)(WQ_N / 8)};
    ca.cum8[0] = 0;
    for (int i = 0; i < 5; i++) ca.cum8[i + 1] = ca.cum8[i] + n8[i];
    int total8 = ca.cum8[5];
    f32_to_f16_multi<<<(total8 + 255) / 256, 256, 0, stream>>>(ca, total8);
    concat_bias<<<(QKVDIM + 255) / 256, 256, 0, stream>>>(bq, bk, bv, bqkv);

    gemm_bt<true><<<dim3(16, 36), 512, 0, stream>>>(hs_h, wqkv_h, bqkv, QKVh, S_LEN, QKVDIM, HDIM);

    rope_spike<<<dim3(S_LEN, 16), 128, 0, stream>>>(QKVh, cosb, sinb, Qa, Ka);
    vtrans<<<dim3(S_LEN / 64, KVDIM / 64), 256, 0, stream>>>(QKVh + HDIM + KVDIM, QKVDIM, Vt);

    attn_kernel<<<dim3(NHEADS, S_LEN / 64), 256, 0, stream>>>(Qa, Ka, Vt, Oattn);

    gemm_bt<false><<<dim3(16, 28), 512, 0, stream>>>(Oattn, wo_h, nullptr, out, S_LEN, HDIM, HDIM);
}